// Round 1
// baseline (221.544 us; speedup 1.0000x reference)
//
#include <hip/hip_runtime.h>

// Viterbi decoder forward: B=32, T=256, L=48, START=46, END=47.
// Two recurrences (Viterbi max/argmax and logsumexp) run in SEPARATE
// workgroups (they share no state until the final score), 64 WGs total.
// Per WG: 4 waves, i-split 12 per wave, lane = target label j.
// best[]/upto[] live in registers by-lane; v_readlane broadcasts best[i].

#define TT 256
#define LL 48
#define LSTART 46
#define LEND 47
#define BB 32

#define LOADBUF(BUF) do { _Pragma("unroll") \
    for (int k = 0; k < 12; ++k) (BUF)[k] = p[k*LL]; \
    p += LL*LL; } while (0)

// One Viterbi step: partial max/argmax over this wave's 12 i's, LDS merge
// across 4 waves (parity double-buffered, one barrier), backpointer byte.
#define STEP_V(BUF) do { \
    float pv = -INFINITY; int pa = 0; \
    _Pragma("unroll") \
    for (int k = 0; k < 12; ++k) { \
      int i = 12*w + k; \
      float bi = __int_as_float(__builtin_amdgcn_readlane(__float_as_int(vbest), i)); \
      float cand = (BUF)[k] + trg[k] + bi; \
      if (cand > pv) { pv = cand; pa = i; } \
    } \
    if (act) partV[par][w][j] = make_float2(pv, __int_as_float(pa)); \
    __syncthreads(); \
    if (act) { \
      float2 m0 = partV[par][0][j]; \
      float bv = m0.x; int ba = __float_as_int(m0.y); \
      _Pragma("unroll") \
      for (int w2 = 1; w2 < 4; ++w2) { \
        float2 mw = partV[par][w2][j]; \
        if (mw.x > bv) { bv = mw.x; ba = __float_as_int(mw.y); } \
      } \
      vbest = bv; \
      if (w == 0) bp[t*LL + j] = (unsigned char)ba; \
    } \
  } while (0)

// One LSE step: single-shift sum of exp (shift = prev wave-max of upto,
// spread across columns is bounded so no under/overflow), LDS merge, log.
#define STEP_L(BUF) do { \
    float ps = 0.f; \
    _Pragma("unroll") \
    for (int k = 0; k < 12; ++k) { \
      int i = 12*w + k; \
      float ui = __int_as_float(__builtin_amdgcn_readlane(__float_as_int(vupto), i)); \
      float x = (BUF)[k] + trg[k] + ui; \
      ps += exp2f((x - msh) * 1.44269504f); \
    } \
    if (act) partS[par][w][j] = ps; \
    __syncthreads(); \
    float sum = partS[par][0][j] + partS[par][1][j] + partS[par][2][j] + partS[par][3][j]; \
    float nu = msh + log2f(sum) * 0.69314718056f; \
    vupto = act ? nu : -INFINITY; \
    float mx = vupto; \
    _Pragma("unroll") \
    for (int d = 1; d < 64; d <<= 1) mx = fmaxf(mx, __shfl_xor(mx, d, 64)); \
    msh = mx; \
  } while (0)

__launch_bounds__(256, 1)
__global__ void viterbi_fwd(const float* __restrict__ em,
                            const float* __restrict__ tr,
                            const int* __restrict__ len_raw,
                            float* __restrict__ out,
                            float* __restrict__ ws)
{
  const int role = blockIdx.x >> 5;   // 0 = Viterbi, 1 = LSE
  const int b    = blockIdx.x & 31;
  const int tid  = threadIdx.x;
  const int w    = tid >> 6;          // wave id: i-block [12w, 12w+12)
  const int j    = tid & 63;          // target label
  const bool act = (j < LL);
  const int jl   = act ? j : (LL - 1);  // clamp for address safety

  // lengths may be stored as int32 or int64; detect (values are 128..256,
  // so int64 storage shows zero high words at odd int32 indices).
  int len;
  {
    bool is64 = (len_raw[1] == 0) && (len_raw[3] == 0) && (len_raw[5] == 0);
    len = is64 ? len_raw[2*b] : len_raw[b];
    if (len > TT) len = TT;
    if (len < 1) len = 1;
  }

  __shared__ float2 partV[2][4][LL];
  __shared__ float  partS[2][4][LL];
  __shared__ unsigned char bp[TT*LL];
  __shared__ unsigned char cmp_[16*LL];
  __shared__ unsigned char entry_[16];
  __shared__ unsigned char raw[TT];

  // transition block for this wave's i-range (constant over t)
  float trg[12];
  #pragma unroll
  for (int k = 0; k < 12; ++k) trg[k] = tr[(12*w + k)*LL + jl];

  // t=0 init: scores[b,0,START,j]
  const float init = em[(size_t)b*TT*LL*LL + LSTART*LL + jl] + tr[LSTART*LL + jl];

  const float* p = em + (size_t)b*TT*LL*LL + (size_t)LL*LL + (size_t)(12*w)*LL + jl;
  float bufA[12], bufB[12];

  if (role == 0) {
    // backpointer rows: row 0 = START (unused by output but keep exact),
    // rows [len, T) = END (masked steps).
    for (int idx = tid; idx < LL; idx += 256) bp[idx] = (unsigned char)LSTART;
    for (int idx = len*LL + tid; idx < TT*LL; idx += 256) bp[idx] = (unsigned char)LEND;

    float vbest = act ? init : -INFINITY;
    int t = 1, par = 0;
    if (t < len) LOADBUF(bufA);
    while (t < len) {
      if (t + 1 < len) LOADBUF(bufB);
      STEP_V(bufA);
      ++t; par ^= 1;
      if (t >= len) break;
      if (t + 1 < len) LOADBUF(bufA);
      STEP_V(bufB);
      ++t; par ^= 1;
    }
    if (tid == LEND) ws[BB + b] = vbest;   // best[END], wave 0 lane 47
    __syncthreads();

    // ---- traceback, chunked (16 chunks x 16 steps) ----
    // Phase A: per-chunk composed maps for every possible entry label.
    for (int idx = tid; idx < 16*LL; idx += 256) {
      int c = idx / LL, l = idx - c*LL;
      int pc = l;
      #pragma unroll
      for (int k = 15; k >= 0; --k) pc = bp[(16*c + k)*LL + pc];
      cmp_[c*LL + l] = (unsigned char)pc;
    }
    __syncthreads();
    // Phase B: serial over 16 chunk boundaries.
    if (tid == 0) {
      int pc = LEND;
      for (int c = 15; c >= 0; --c) { entry_[c] = (unsigned char)pc; pc = cmp_[c*LL + pc]; }
    }
    __syncthreads();
    // Phase C: re-walk chunks in parallel, record raw decoded labels.
    if (tid < 16) {
      int c = tid, pc = entry_[c];
      #pragma unroll
      for (int k = 15; k >= 0; --k) { int t2 = 16*c + k; pc = bp[t2*LL + pc]; raw[t2] = (unsigned char)pc; }
    }
    __syncthreads();
    // output shift: out[t] = raw[t+1], out[T-1] = END
    out[(size_t)b*TT + tid] = (tid < TT - 1) ? (float)raw[tid + 1] : (float)LEND;
  } else {
    float vupto = act ? init : -INFINITY;
    float msh;
    {
      float mx = vupto;
      #pragma unroll
      for (int d = 1; d < 64; d <<= 1) mx = fmaxf(mx, __shfl_xor(mx, d, 64));
      msh = mx;
    }
    int t = 1, par = 0;
    if (t < len) LOADBUF(bufA);
    while (t < len) {
      if (t + 1 < len) LOADBUF(bufB);
      STEP_L(bufA);
      ++t; par ^= 1;
      if (t >= len) break;
      if (t + 1 < len) LOADBUF(bufA);
      STEP_L(bufB);
      ++t; par ^= 1;
    }
    if (tid == LEND) ws[b] = vupto;        // upto[END]
  }
}

__global__ void viterbi_score(const float* __restrict__ ws, float* __restrict__ out)
{
  int b = threadIdx.x;
  if (b < BB) out[(size_t)BB*TT + b] = ws[BB + b] - ws[b];  // -(upto-best)
}

extern "C" void kernel_launch(void* const* d_in, const int* in_sizes, int n_in,
                              void* d_out, int out_size, void* d_ws, size_t ws_size,
                              hipStream_t stream) {
  const float* em  = (const float*)d_in[0];
  const float* tr  = (const float*)d_in[1];
  const int*   ln  = (const int*)d_in[2];
  float* out = (float*)d_out;
  float* ws  = (float*)d_ws;
  viterbi_fwd<<<dim3(64), dim3(256), 0, stream>>>(em, tr, ln, out, ws);
  viterbi_score<<<dim3(1), dim3(64), 0, stream>>>(ws, out);
}

// Round 2
// 178.645 us; speedup vs baseline: 1.2401x; 1.2401x over previous
//
#include <hip/hip_runtime.h>

// Viterbi decoder forward: B=32, T=256, L=48, START=46, END=47.
// Roles: 32 WGs Viterbi (max/argmax + traceback), 32 WGs logsumexp.
// Per WG: 4 waves, i-split 12 per wave, lane = target label j.
// Key: RAW barriers (no vmcnt drain) so global prefetch stays in flight;
// 4-deep register double... quad-buffer; tree argmax; readlane LSE shift.

#define TT 256
#define LL 48
#define LSTART 46
#define LEND 47
#define BB 32

// lgkmcnt(0) orders LDS write->barrier->read; vmcnt NOT drained, so the
// global prefetch loads issued in LOADBUF stay outstanding across steps.
#define BARRIER() do { \
    asm volatile("s_waitcnt lgkmcnt(0)" ::: "memory"); \
    __builtin_amdgcn_s_barrier(); \
  } while (0)

#define LOADBUF(BUF) do { _Pragma("unroll") \
    for (int k = 0; k < 12; ++k) (BUF)[k] = p[k*LL]; \
    p += LL*LL; } while (0)

// strict > : later operand wins only if strictly greater -> with left
// index < right index pairing this is exact first-occurrence argmax.
#define AMAX(vx, ix, vy, iy) do { \
    if ((vy) > (vx)) { (vx) = (vy); (ix) = (iy); } } while (0)

#define RL(var, lane) __int_as_float(__builtin_amdgcn_readlane(__float_as_int(var), (lane)))

// One Viterbi step: 12 candidates, depth-4 tree argmax, LDS merge across
// 4 waves (parity double-buffered, one raw barrier), backpointer byte.
#define STEP_V(BUF) do { \
    float cv[12]; int ci[12]; \
    _Pragma("unroll") \
    for (int k = 0; k < 12; ++k) { \
      cv[k] = (BUF)[k] + trg[k] + RL(vbest, 12*w + k); \
      ci[k] = 12*w + k; \
    } \
    AMAX(cv[0],ci[0],cv[1],ci[1]);  AMAX(cv[2],ci[2],cv[3],ci[3]); \
    AMAX(cv[4],ci[4],cv[5],ci[5]);  AMAX(cv[6],ci[6],cv[7],ci[7]); \
    AMAX(cv[8],ci[8],cv[9],ci[9]);  AMAX(cv[10],ci[10],cv[11],ci[11]); \
    AMAX(cv[0],ci[0],cv[2],ci[2]);  AMAX(cv[4],ci[4],cv[6],ci[6]); \
    AMAX(cv[8],ci[8],cv[10],ci[10]); \
    AMAX(cv[0],ci[0],cv[4],ci[4]); \
    AMAX(cv[0],ci[0],cv[8],ci[8]); \
    if (act) partV[par][w][j] = make_float2(cv[0], __int_as_float(ci[0])); \
    BARRIER(); \
    if (act) { \
      float2 m0 = partV[par][0][j], m1 = partV[par][1][j]; \
      float2 m2 = partV[par][2][j], m3 = partV[par][3][j]; \
      float bv = m0.x; int ba = __float_as_int(m0.y); \
      AMAX(bv, ba, m1.x, __float_as_int(m1.y)); \
      AMAX(bv, ba, m2.x, __float_as_int(m2.y)); \
      AMAX(bv, ba, m3.x, __float_as_int(m3.y)); \
      vbest = bv; \
      if (w == 0) bp[t*LL + j] = (unsigned char)ba; \
    } \
  } while (0)

// One LSE step: single-shift sum of exp; shift = upto[0] (readlane), which
// bounds exp args (spread of upto across labels <= score range, ~30 nats).
#define STEP_L(BUF) do { \
    float e[12]; \
    _Pragma("unroll") \
    for (int k = 0; k < 12; ++k) { \
      float x = (BUF)[k] + trg[k] + RL(vupto, 12*w + k); \
      e[k] = exp2f((x - msh) * 1.44269504f); \
    } \
    float s01 = e[0]+e[1], s23 = e[2]+e[3], s45 = e[4]+e[5]; \
    float s67 = e[6]+e[7], s89 = e[8]+e[9], sab = e[10]+e[11]; \
    float ps = ((s01+s23)+(s45+s67)) + (s89+sab); \
    if (act) partS[par][w][j] = ps; \
    BARRIER(); \
    float sum = partS[par][0][j] + partS[par][1][j] \
              + partS[par][2][j] + partS[par][3][j]; \
    float nu = msh + log2f(sum) * 0.69314718056f; \
    vupto = act ? nu : -INFINITY; \
    msh = RL(vupto, 0); \
  } while (0)

__launch_bounds__(256, 1)
__global__ void viterbi_fwd(const float* __restrict__ em,
                            const float* __restrict__ tr,
                            const int* __restrict__ len_raw,
                            float* __restrict__ out,
                            float* __restrict__ ws)
{
  const int role = blockIdx.x >> 5;   // 0 = Viterbi, 1 = LSE
  const int b    = blockIdx.x & 31;
  const int tid  = threadIdx.x;
  const int w    = tid >> 6;          // wave id: i-block [12w, 12w+12)
  const int j    = tid & 63;          // target label
  const bool act = (j < LL);
  const int jl   = act ? j : (LL - 1);  // clamp for address safety

  // lengths may be stored as int32 or int64 (values 128..256 -> int64
  // storage shows zero high words at odd int32 indices).
  int len;
  {
    bool is64 = (len_raw[1] == 0) && (len_raw[3] == 0) && (len_raw[5] == 0);
    len = is64 ? len_raw[2*b] : len_raw[b];
    if (len > TT) len = TT;
    if (len < 1) len = 1;
  }

  __shared__ float2 partV[2][4][LL];
  __shared__ float  partS[2][4][LL];
  __shared__ unsigned char bp[TT*LL];
  __shared__ unsigned char cmp_[16*LL];
  __shared__ unsigned char entry_[16];
  __shared__ unsigned char raw[TT];

  // transition block for this wave's i-range (constant over t)
  float trg[12];
  #pragma unroll
  for (int k = 0; k < 12; ++k) trg[k] = tr[(12*w + k)*LL + jl];

  // t=0 init: scores[b,0,START,j]
  const float init = em[(size_t)b*TT*LL*LL + LSTART*LL + jl] + tr[LSTART*LL + jl];

  const float* p = em + (size_t)b*TT*LL*LL + (size_t)LL*LL + (size_t)(12*w)*LL + jl;
  float b0[12], b1[12], b2[12], b3[12];

  if (role == 0) {
    // backpointer rows: row 0 = START; rows [len, T) = END (masked steps).
    for (int idx = tid; idx < LL; idx += 256) bp[idx] = (unsigned char)LSTART;
    for (int idx = len*LL + tid; idx < TT*LL; idx += 256) bp[idx] = (unsigned char)LEND;

    float vbest = act ? init : -INFINITY;
    int t = 1, par = 0;
    if (t     < len) LOADBUF(b0);
    if (t + 1 < len) LOADBUF(b1);
    if (t + 2 < len) LOADBUF(b2);
    while (t < len) {
      if (t + 3 < len) LOADBUF(b3);
      STEP_V(b0); ++t; par ^= 1; if (t >= len) break;
      if (t + 3 < len) LOADBUF(b0);
      STEP_V(b1); ++t; par ^= 1; if (t >= len) break;
      if (t + 3 < len) LOADBUF(b1);
      STEP_V(b2); ++t; par ^= 1; if (t >= len) break;
      if (t + 3 < len) LOADBUF(b2);
      STEP_V(b3); ++t; par ^= 1;
    }
    if (tid == LEND) ws[BB + b] = vbest;   // best[END]
    __syncthreads();

    // ---- traceback, chunked (16 chunks x 16 steps) ----
    for (int idx = tid; idx < 16*LL; idx += 256) {
      int c = idx / LL, l = idx - c*LL;
      int pc = l;
      #pragma unroll
      for (int k = 15; k >= 0; --k) pc = bp[(16*c + k)*LL + pc];
      cmp_[c*LL + l] = (unsigned char)pc;
    }
    __syncthreads();
    if (tid == 0) {
      int pc = LEND;
      for (int c = 15; c >= 0; --c) { entry_[c] = (unsigned char)pc; pc = cmp_[c*LL + pc]; }
    }
    __syncthreads();
    if (tid < 16) {
      int c = tid, pc = entry_[c];
      #pragma unroll
      for (int k = 15; k >= 0; --k) { int t2 = 16*c + k; pc = bp[t2*LL + pc]; raw[t2] = (unsigned char)pc; }
    }
    __syncthreads();
    // output shift: out[t] = raw[t+1], out[T-1] = END
    out[(size_t)b*TT + tid] = (tid < TT - 1) ? (float)raw[tid + 1] : (float)LEND;
  } else {
    float vupto = act ? init : -INFINITY;
    float msh = RL(vupto, 0);
    int t = 1, par = 0;
    if (t     < len) LOADBUF(b0);
    if (t + 1 < len) LOADBUF(b1);
    if (t + 2 < len) LOADBUF(b2);
    while (t < len) {
      if (t + 3 < len) LOADBUF(b3);
      STEP_L(b0); ++t; par ^= 1; if (t >= len) break;
      if (t + 3 < len) LOADBUF(b0);
      STEP_L(b1); ++t; par ^= 1; if (t >= len) break;
      if (t + 3 < len) LOADBUF(b1);
      STEP_L(b2); ++t; par ^= 1; if (t >= len) break;
      if (t + 3 < len) LOADBUF(b2);
      STEP_L(b3); ++t; par ^= 1;
    }
    if (tid == LEND) ws[b] = vupto;        // upto[END]
  }
}

__global__ void viterbi_score(const float* __restrict__ ws, float* __restrict__ out)
{
  int b = threadIdx.x;
  if (b < BB) out[(size_t)BB*TT + b] = ws[BB + b] - ws[b];  // best - upto
}

extern "C" void kernel_launch(void* const* d_in, const int* in_sizes, int n_in,
                              void* d_out, int out_size, void* d_ws, size_t ws_size,
                              hipStream_t stream) {
  const float* em  = (const float*)d_in[0];
  const float* tr  = (const float*)d_in[1];
  const int*   ln  = (const int*)d_in[2];
  float* out = (float*)d_out;
  float* ws  = (float*)d_ws;
  viterbi_fwd<<<dim3(64), dim3(256), 0, stream>>>(em, tr, ln, out, ws);
  viterbi_score<<<dim3(1), dim3(64), 0, stream>>>(ws, out);
}

// Round 3
// 144.316 us; speedup vs baseline: 1.5351x; 1.2379x over previous
//
#include <hip/hip_runtime.h>

// Viterbi decoder forward: B=32, T=256, L=48, START=46, END=47.
// Roles: 32 WGs Viterbi (max/argmax + traceback), 32 WGs logsumexp.
// Per WG: 4 waves, i-split 12 per wave, lane = target label j.
// Round-3 change: FIXED 255-step loop, ALL global loads unconditional
// (address-clamped, never execution-masked) so the compiler can emit
// counted s_waitcnt vmcnt(N) and the 4-deep register prefetch survives;
// state updates masked by uniform t<len. Raw lgkm-only barriers.

#define TT 256
#define LL 48
#define LSTART 46
#define LEND 47
#define BB 32
#define NL 64   // padded label columns for branch-free LDS stores

// lgkmcnt(0) orders LDS write->barrier->read; vmcnt NOT drained, so the
// global prefetch loads stay outstanding across steps.
#define BARRIER() do { \
    asm volatile("s_waitcnt lgkmcnt(0)" ::: "memory"); \
    __builtin_amdgcn_s_barrier(); \
  } while (0)

// Unconditional load of emission row ROW (clamped to last valid row, so
// tail prefetches are safe); 12 dwords per lane, immediate k*192B offsets.
#define LOADROW(BUF, ROW) do { \
    int r_ = (ROW) < (TT - 1) ? (ROW) : (TT - 1); \
    const float* q_ = base + (size_t)r_ * (LL*LL); \
    _Pragma("unroll") \
    for (int k = 0; k < 12; ++k) (BUF)[k] = q_[k*LL]; \
  } while (0)

// strict > : with left index < right index pairing this reproduces
// jnp.argmax first-occurrence semantics exactly.
#define AMAX(vx, ix, vy, iy) do { \
    if ((vy) > (vx)) { (vx) = (vy); (ix) = (iy); } } while (0)

#define RL(var, lane) __int_as_float(__builtin_amdgcn_readlane(__float_as_int(var), (lane)))

// One Viterbi step: 12 candidates, depth-4 tree argmax, LDS merge across
// 4 waves (compile-time parity PAR, one raw barrier), masked state update.
#define STEP_V(BUF, T_, PAR) do { \
    float cv[12]; int ci[12]; \
    _Pragma("unroll") \
    for (int k = 0; k < 12; ++k) { \
      cv[k] = (BUF)[k] + trg[k] + RL(vbest, 12*w + k); \
      ci[k] = 12*w + k; \
    } \
    AMAX(cv[0],ci[0],cv[1],ci[1]);  AMAX(cv[2],ci[2],cv[3],ci[3]); \
    AMAX(cv[4],ci[4],cv[5],ci[5]);  AMAX(cv[6],ci[6],cv[7],ci[7]); \
    AMAX(cv[8],ci[8],cv[9],ci[9]);  AMAX(cv[10],ci[10],cv[11],ci[11]); \
    AMAX(cv[0],ci[0],cv[2],ci[2]);  AMAX(cv[4],ci[4],cv[6],ci[6]); \
    AMAX(cv[8],ci[8],cv[10],ci[10]); \
    AMAX(cv[0],ci[0],cv[4],ci[4]); \
    AMAX(cv[0],ci[0],cv[8],ci[8]); \
    partV[PAR][w][j] = make_float2(cv[0], __int_as_float(ci[0])); \
    BARRIER(); \
    float2 m0 = partV[PAR][0][j], m1 = partV[PAR][1][j]; \
    float2 m2 = partV[PAR][2][j], m3 = partV[PAR][3][j]; \
    float bv = m0.x; int ba = __float_as_int(m0.y); \
    AMAX(bv, ba, m1.x, __float_as_int(m1.y)); \
    AMAX(bv, ba, m2.x, __float_as_int(m2.y)); \
    AMAX(bv, ba, m3.x, __float_as_int(m3.y)); \
    bool upd = act && ((T_) < len); \
    vbest = upd ? bv : vbest; \
    if (w == 0 && upd) bp[(T_)*LL + j] = (unsigned char)ba; \
  } while (0)

// One LSE step: single-shift sum of exp; shift = upto[0] (readlane) bounds
// exp args (spread of upto across labels <= per-step score range).
#define STEP_L(BUF, T_, PAR) do { \
    float e[12]; \
    _Pragma("unroll") \
    for (int k = 0; k < 12; ++k) { \
      float x = (BUF)[k] + trg[k] + RL(vupto, 12*w + k); \
      e[k] = exp2f((x - msh) * 1.44269504f); \
    } \
    float s01 = e[0]+e[1], s23 = e[2]+e[3], s45 = e[4]+e[5]; \
    float s67 = e[6]+e[7], s89 = e[8]+e[9], sab = e[10]+e[11]; \
    float ps = ((s01+s23)+(s45+s67)) + (s89+sab); \
    partS[PAR][w][j] = ps; \
    BARRIER(); \
    float sum = partS[PAR][0][j] + partS[PAR][1][j] \
              + partS[PAR][2][j] + partS[PAR][3][j]; \
    float nu = msh + log2f(sum) * 0.69314718056f; \
    bool upd = act && ((T_) < len); \
    vupto = upd ? nu : vupto; \
    msh = RL(vupto, 0); \
  } while (0)

__launch_bounds__(256, 1)
__global__ void viterbi_fwd(const float* __restrict__ em,
                            const float* __restrict__ tr,
                            const int* __restrict__ len_raw,
                            float* __restrict__ out,
                            float* __restrict__ ws)
{
  const int role = blockIdx.x >> 5;   // 0 = Viterbi, 1 = LSE
  const int b    = blockIdx.x & 31;
  const int tid  = threadIdx.x;
  const int w    = tid >> 6;          // wave id: i-block [12w, 12w+12)
  const int j    = tid & 63;          // target label (padded to 64)
  const bool act = (j < LL);
  const int jl   = act ? j : (LL - 1);  // clamp for address safety

  // lengths may be stored as int32 or int64 (values 128..256 -> int64
  // storage shows zero high words at odd int32 indices).
  int len;
  {
    bool is64 = (len_raw[1] == 0) && (len_raw[3] == 0) && (len_raw[5] == 0);
    len = is64 ? len_raw[2*b] : len_raw[b];
    if (len > TT) len = TT;
    if (len < 1) len = 1;
  }

  __shared__ float2 partV[2][4][NL];
  __shared__ float  partS[2][4][NL];
  __shared__ unsigned char bp[TT*LL];
  __shared__ unsigned char cmp_[16*LL];
  __shared__ unsigned char entry_[16];
  __shared__ unsigned char raw[TT];

  // transition block for this wave's i-range (constant over t)
  float trg[12];
  #pragma unroll
  for (int k = 0; k < 12; ++k) trg[k] = tr[(12*w + k)*LL + jl];

  // t=0 init: scores[b,0,START,j]
  const float init = em[(size_t)b*TT*LL*LL + LSTART*LL + jl] + tr[LSTART*LL + jl];

  // per-wave base of emission row 0 for this WG's batch
  const float* base = em + (size_t)b*TT*LL*LL + (size_t)(12*w)*LL + jl;
  float b0[12], b1[12], b2[12], b3[12];

  if (role == 0) {
    // backpointer rows: row 0 = START; rows [len, T) = END (masked steps).
    for (int idx = tid; idx < LL; idx += 256) bp[idx] = (unsigned char)LSTART;
    for (int idx = len*LL + tid; idx < TT*LL; idx += 256) bp[idx] = (unsigned char)LEND;

    float vbest = act ? init : -INFINITY;
    LOADROW(b0, 1); LOADROW(b1, 2); LOADROW(b2, 3);
    int t = 1;
    #pragma unroll 1
    for (int it = 0; it < 63; ++it) {
      LOADROW(b3, t + 3); STEP_V(b0, t,     0);
      LOADROW(b0, t + 4); STEP_V(b1, t + 1, 1);
      LOADROW(b1, t + 5); STEP_V(b2, t + 2, 0);
      LOADROW(b2, t + 6); STEP_V(b3, t + 3, 1);
      t += 4;
    }
    // t == 253: tail steps, buffers already loaded (rows 253,254,255)
    STEP_V(b0, 253, 0); STEP_V(b1, 254, 1); STEP_V(b2, 255, 0);

    if (tid == LEND) ws[BB + b] = vbest;   // best[END]
    __syncthreads();

    // ---- traceback, chunked (16 chunks x 16 steps) ----
    for (int idx = tid; idx < 16*LL; idx += 256) {
      int c = idx / LL, l = idx - c*LL;
      int pc = l;
      #pragma unroll
      for (int k = 15; k >= 0; --k) pc = bp[(16*c + k)*LL + pc];
      cmp_[c*LL + l] = (unsigned char)pc;
    }
    __syncthreads();
    if (tid == 0) {
      int pc = LEND;
      for (int c = 15; c >= 0; --c) { entry_[c] = (unsigned char)pc; pc = cmp_[c*LL + pc]; }
    }
    __syncthreads();
    if (tid < 16) {
      int c = tid, pc = entry_[c];
      #pragma unroll
      for (int k = 15; k >= 0; --k) { int t2 = 16*c + k; pc = bp[t2*LL + pc]; raw[t2] = (unsigned char)pc; }
    }
    __syncthreads();
    // output shift: out[t] = raw[t+1], out[T-1] = END
    out[(size_t)b*TT + tid] = (tid < TT - 1) ? (float)raw[tid + 1] : (float)LEND;
  } else {
    float vupto = act ? init : -INFINITY;
    float msh = RL(vupto, 0);
    LOADROW(b0, 1); LOADROW(b1, 2); LOADROW(b2, 3);
    int t = 1;
    #pragma unroll 1
    for (int it = 0; it < 63; ++it) {
      LOADROW(b3, t + 3); STEP_L(b0, t,     0);
      LOADROW(b0, t + 4); STEP_L(b1, t + 1, 1);
      LOADROW(b1, t + 5); STEP_L(b2, t + 2, 0);
      LOADROW(b2, t + 6); STEP_L(b3, t + 3, 1);
      t += 4;
    }
    STEP_L(b0, 253, 0); STEP_L(b1, 254, 1); STEP_L(b2, 255, 0);

    if (tid == LEND) ws[b] = vupto;        // upto[END]
  }
}

__global__ void viterbi_score(const float* __restrict__ ws, float* __restrict__ out)
{
  int b = threadIdx.x;
  if (b < BB) out[(size_t)BB*TT + b] = ws[BB + b] - ws[b];  // best - upto
}

extern "C" void kernel_launch(void* const* d_in, const int* in_sizes, int n_in,
                              void* d_out, int out_size, void* d_ws, size_t ws_size,
                              hipStream_t stream) {
  const float* em  = (const float*)d_in[0];
  const float* tr  = (const float*)d_in[1];
  const int*   ln  = (const int*)d_in[2];
  float* out = (float*)d_out;
  float* ws  = (float*)d_ws;
  viterbi_fwd<<<dim3(64), dim3(256), 0, stream>>>(em, tr, ln, out, ws);
  viterbi_score<<<dim3(1), dim3(64), 0, stream>>>(ws, out);
}